// Round 10
// baseline (221.765 us; speedup 1.0000x reference)
//
#include <hip/hip_runtime.h>

#define HH 128
#define WW 128
#define CC 64
#define BS 512
#define RS (WW * CC)    // row stride in floats
#define NPT 4           // contiguous w-points per thread
#define NSTRIP 32       // strips per row (NSTRIP * NPT == WW)
#define ROWS 8          // image rows per block (grid = 16*128/ROWS = 256 = 1/CU)

typedef float f4 __attribute__((ext_vector_type(4)));

static __device__ __forceinline__ f4 vload(const float* p) {
    return *reinterpret_cast<const f4*>(p);
}
static __device__ __forceinline__ void vstore(float* p, f4 v) {
    *reinterpret_cast<f4*>(p) = v;
}
static __device__ __forceinline__ f4 vrelu(f4 a) {
    f4 r;
    #pragma unroll
    for (int i = 0; i < 4; ++i) r[i] = fmaxf(a[i], 0.f);
    return r;
}
static __device__ __forceinline__ f4 vrsq_eps(f4 a) {   // 1/sqrt(a+eps), HW v_rsq_f32
    f4 r;
    #pragma unroll
    for (int i = 0; i < 4; ++i) r[i] = __builtin_amdgcn_rsqf(a[i] + 1e-3f);
    return r;
}
static __device__ __forceinline__ f4 vrcp(f4 a) {       // 1/a, HW v_rcp_f32
    f4 r;
    #pragma unroll
    for (int i = 0; i < 4; ++i) r[i] = __builtin_amdgcn_rcpf(a[i]);
    return r;
}
// Channel-roll (c+-1 wrap over 64 ch) of an f4 held across a 16-lane cq group.
static __device__ __forceinline__ void croll(f4 v, int lm, int lp, f4& cm, f4& cp) {
    const float m3 = __shfl(v.w, lm);
    const float p0 = __shfl(v.x, lp);
    cm.x = m3;  cm.y = v.x; cm.z = v.y; cm.w = v.z;
    cp.x = v.y; cp.y = v.z; cp.z = v.w; cp.w = p0;
}
static __device__ __forceinline__ f4 shfl4(f4 v, int lane) {
    f4 r;
    r.x = __shfl(v.x, lane);
    r.y = __shfl(v.y, lane);
    r.z = __shfl(v.z, lane);
    r.w = __shfl(v.w, lane);
    return r;
}

// async global->LDS DMA, 16 B/lane; LDS dest = wave-uniform base + lane*16 (m03/m97)
static __device__ __forceinline__ void gld_lds16(const float* g, float* l) {
    __builtin_amdgcn_global_load_lds(
        (const __attribute__((address_space(1))) void*)g,
        (__attribute__((address_space(3))) void*)l,
        16, 0, 0);
}
// copy one 32 KB image row into an LDS ring slot (4 x 1 KB chunks per wave)
static __device__ __forceinline__ void stage_row(const float* g, float* l,
                                                 int wv, int ln) {
    #pragma unroll
    for (int it = 0; it < 4; ++it) {
        const int off = (it * 8 + wv) * 256;   // float offset, wave-uniform
        gld_lds16(g + off + ln * 4, l + off);
    }
}

// 3 taps (one conv row): g/g1 weights from REGISTERS (static idx), Dx/Dy from LDS.
template<int KBASE, bool CENTER>
static __device__ __forceinline__ void conv_taps(
    const float* R, const f4* wgr, const f4* wg1r, const float* WTS,
    const int* oc, bool zl, bool zr, int c4,
    f4* ag, f4* ag1, f4* adx, f4* ady, f4* h)
{
    f4 in[6];
    #pragma unroll
    for (int jj = 0; jj < 6; ++jj) in[jj] = vload(R + oc[jj]);
    if (zl) in[0] = (f4)0.f;     // zero pad, cndmask
    if (zr) in[5] = (f4)0.f;
    if (CENTER) {
        #pragma unroll
        for (int i = 0; i < NPT; ++i) h[i] = in[i + 1];   // f
    }
    #pragma unroll
    for (int dw = 0; dw < 3; ++dw) {
        const int kk = KBASE + dw;                        // compile-time
        const f4 wg  = wgr[kk];
        const f4 wg1 = wg1r[kk];
        const f4 wdx = vload(WTS + kk * CC + c4);
        const f4 wdy = vload(WTS + (9 + kk) * CC + c4);
        #pragma unroll
        for (int i = 0; i < NPT; ++i) {
            ag[i]  += in[dw + i] * wg;
            ag1[i] += in[dw + i] * wg1;
            adx[i] += in[dw + i] * wdx;
            ady[i] += in[dw + i] * wdy;
        }
    }
}

// NOTE (r2): pinning HIGH min-waves (8) squeezed VGPR -> catastrophic spill.
// NOTE (r8): weights-in-regs spilled because DEFAULT cap was 128 VGPR.
// NOTE (r9): LDS already limits to 1 block/CU = 2 waves/SIMD, so
// __launch_bounds__(BS, 2) RAISES the VGPR cap to 256 at zero occupancy cost.
// This round: r9 + g/g1 weights & BN folds promoted to registers (~216 VGPR),
// cutting loop-invariant ds_reads 46/row -> ~18/row.
__global__ __launch_bounds__(BS, 2) void diffusion_fused(
    const float* __restrict__ s0,
    const float* __restrict__ kg,  const float* __restrict__ kg1,
    const float* __restrict__ kDx, const float* __restrict__ kDy,
    const float* __restrict__ bng,  const float* __restrict__ bng1,
    const float* __restrict__ bnDx, const float* __restrict__ bnDy,
    const float* __restrict__ bn_out,
    float* __restrict__ out)
{
    __shared__ __attribute__((aligned(16))) float ring[4][RS];     // 128 KB, slot(row x) = x&3
    __shared__ __attribute__((aligned(16))) float GHS[8 * CC];     // 2 KB g first-col per wave
    __shared__ __attribute__((aligned(16))) float GHE[8 * CC];     // 2 KB g last-col per wave
    __shared__ __attribute__((aligned(16))) float HBS[8 * CC];     // 2 KB h1 first-col per wave
    __shared__ __attribute__((aligned(16))) float HBE[8 * CC];     // 2 KB h1 last-col per wave
    __shared__ __attribute__((aligned(16))) float WTS[2 * 9 * CC]; // 4.5 KB Dx/Dy weights

    const int t  = threadIdx.x;
    const int cq = t & 15;
    const int c4 = cq << 2;              // channels c4..c4+3
    const int s  = t >> 4;               // strip 0..31
    const int w0 = s << 2;               // output columns w0..w0+3
    const int l  = t & 63;
    const int wv = t >> 6;               // wave 0..7 (wave owns strips 4wv..4wv+3)
    const int jg = l >> 4;               // strip slot within wave 0..3
    const int lm = (l & 48) | ((l + 15) & 15);   // channel-roll shuffle lanes
    const int lp = (l & 48) | ((l + 1)  & 15);

    const int bid = blockIdx.x;
    const int img = bid >> 4;            // 16 row-groups per image
    const int r0  = (bid & 15) << 3;     // first row of this block's group
    const long imgbase = (long)img * HH * RS;

    // column offsets for the 6-column window w0-1 .. w0+4 (clamped; pad zeroed)
    const bool zl = (s == 0), zr = (s == NSTRIP - 1);
    int oc[6];
    oc[0] = (zl ? 0 : (w0 - 1)) * CC + c4;
    #pragma unroll
    for (int j = 1; j <= 4; ++j) oc[j] = (w0 + j - 1) * CC + c4;
    oc[5] = (zr ? (WW - 1) : (w0 + 4)) * CC + c4;
    const int wmo = ((w0 - 1) & (WW - 1)) * CC + c4;   // wrap left col (roll semantics)
    const int wpo = ((w0 + 4) & (WW - 1)) * CC + c4;   // wrap right col

    // ---- prologue ----
    if (r0 > 0)
        stage_row(s0 + imgbase + (long)(r0 - 1) * RS, ring[(r0 - 1) & 3], wv, l);
    stage_row(s0 + imgbase + (long)r0 * RS,       ring[r0 & 3],       wv, l);
    stage_row(s0 + imgbase + (long)(r0 + 1) * RS, ring[(r0 + 1) & 3], wv, l);

    // g/g1 weights -> registers (once per block; all indexing static via KBASE)
    f4 wgr[9], wg1r[9];
    #pragma unroll
    for (int kk = 0; kk < 9; ++kk) {
        wgr[kk]  = vload(kg  + kk * CC + c4);
        wg1r[kk] = vload(kg1 + kk * CC + c4);
    }
    // Dx/Dy weights -> LDS (288 f4 slots)
    if (t < 288) {
        const int q   = (t >= 144);
        const int rem = t - q * 144;
        const int kk  = rem >> 4;
        const int cc4 = (rem & 15) << 2;
        const float* src = q ? kDy : kDx;
        vstore(&WTS[(q * 9 + kk) * CC + cc4], vload(src + kk * CC + cc4));
    }
    // BN folds -> registers (per-thread, y = S*x + B; 2*DT folded into Dx/Dy)
    #define BNFOLD(P, S, B, SC) { \
        const f4 ga = vload((P) + c4);       const f4 be = vload((P) + 64 + c4);  \
        const f4 mu = vload((P) + 128 + c4); const f4 va = vload((P) + 192 + c4); \
        const f4 sc0 = ga * vrsq_eps(va);                                         \
        S = sc0 * (SC);  B = (be - mu * sc0) * (SC); }
    f4 s_g, b_g, s_g1, b_g1, s_dx, b_dx, s_dy, b_dy, s_o, b_o;
    BNFOLD(bng,    s_g,  b_g,  1.0f);
    BNFOLD(bng1,   s_g1, b_g1, 1.0f);
    BNFOLD(bnDx,   s_dx, b_dx, 0.4f);
    BNFOLD(bnDy,   s_dy, b_dy, 0.4f);
    BNFOLD(bn_out, s_o,  b_o,  1.0f);
    #undef BNFOLD
    __syncthreads();   // prologue staging + WTS visible

    // ---- row loop: 2 barriers/row; stage(gr+2) issued at TOP, drains at A ----
    for (int j = 0; j < ROWS; ++j) {
        const int gr = r0 + j;
        // slot (gr+2)&3 == slot (gr-2)&3: last read in row j-1's conv, which
        // retired before row j-1's barrier A -> safe to overwrite here.
        if (j < ROWS - 1 && gr + 2 < HH)
            stage_row(s0 + imgbase + (long)(gr + 2) * RS, ring[(gr + 2) & 3], wv, l);

        const bool rowm = (gr > 0), rowp = (gr < HH - 1);
        const float* Rm = ring[(gr + 3) & 3];   // row gr-1
        const float* Rc = ring[gr & 3];         // row gr
        const float* Rp = ring[(gr + 1) & 3];   // row gr+1

        f4 ag[NPT], ag1[NPT], adx[NPT], ady[NPT], h[NPT];
        #pragma unroll
        for (int i = 0; i < NPT; ++i) {
            ag[i] = (f4)0.f; ag1[i] = (f4)0.f; adx[i] = (f4)0.f; ady[i] = (f4)0.f;
        }
        if (rowm) conv_taps<0, false>(Rm, wgr, wg1r, WTS, oc, zl, zr, c4, ag, ag1, adx, ady, h);
        conv_taps<3, true >(Rc, wgr, wg1r, WTS, oc, zl, zr, c4, ag, ag1, adx, ady, h);
        if (rowp) conv_taps<6, false>(Rp, wgr, wg1r, WTS, oc, zl, zr, c4, ag, ag1, adx, ady, h);

        // f W-edge neighbors straight from resident ring row (no barrier dep)
        const f4 hL = vload(Rc + wmo);
        const f4 hR = vload(Rc + wpo);

        // BN apply + g/g1 (folds in registers); publish wave-edge g halos
        f4 g[NPT], g1[NPT];
        #pragma unroll
        for (int i = 0; i < NPT; ++i) {
            g[i]  = vrelu(ag[i]  * s_g  + b_g );
            g1[i] = vrelu(ag1[i] * s_g1 + b_g1);
        }
        if (jg == 0) vstore(&GHS[wv * CC + c4], g[0]);
        if (jg == 3) vstore(&GHE[wv * CC + c4], g[3]);
        // wave-sync shuffles for interior strip edges
        const f4 gLs = shfl4(g[3], (l - 16) & 63);
        const f4 gRs = shfl4(g[0], (l + 16) & 63);

        // per-point PDE coefficients (verbatim r5/r7/r9 numerics)
        f4 cWm[NPT], cWp[NPT], cCm[NPT], cCp[NPT], A0[NPT], PqD[NPT], uv[NPT];
        #pragma unroll
        for (int i = 0; i < NPT; ++i) {
            const f4 tbx = vrelu(adx[i] * s_dx + b_dx);   // = 2*DT*Dx
            const f4 tby = vrelu(ady[i] * s_dy + b_dy);   // = 2*DT*Dy
            const f4 Dv  = vrcp((f4)1.f + tbx + tby);
            const f4 Ax  = g[i]  * 0.2f;
            const f4 Ay  = g1[i] * 0.2f;
            cWm[i] = Dv * (tbx - Ax);
            cWp[i] = Dv * (tbx + Ax);
            cCm[i] = Dv * (tby - Ay);
            cCp[i] = Dv * (tby + Ay);
            A0[i]  = Dv * h[i] * ((f4)1.4f - tbx - tby);  // h0 == f both iters (K=2 lag)
            PqD[i] = Dv * (-0.4f);
            f4 cm, cp;
            croll(g1[i], lm, lp, cm, cp);
            uv[i] = 0.5f * (cm - cp);                     // vy part
        }
        uv[0] -= 0.5f * g[1];
        uv[1] += 0.5f * (g[0] - g[2]);
        uv[2] += 0.5f * (g[1] - g[3]);
        uv[3] += 0.5f * g[2];
        __syncthreads();   // A: g halos visible; stage DMA for row gr+2 drained

        // cE from ux edges (LDS only for wave-edge strips)
        const f4 gL = (jg == 0) ? vload(&GHE[((wv + 7) & 7) * CC + c4]) : gLs;
        const f4 gR = (jg == 3) ? vload(&GHS[((wv + 1) & 7) * CC + c4]) : gRs;
        f4 cE[NPT];
        cE[0] = PqD[0] * (uv[0] + 0.5f * gL);
        cE[1] = PqD[1] * uv[1];
        cE[2] = PqD[2] * uv[2];
        cE[3] = PqD[3] * (uv[3] - 0.5f * gR);

        // PDE iter 1 (h == f)
        f4 hn[NPT];
        #pragma unroll
        for (int i = 0; i < NPT; ++i) {
            const f4 hm = (i == 0)       ? hL : h[i - 1];
            const f4 hp = (i == NPT - 1) ? hR : h[i + 1];
            f4 cm, cp;
            croll(h[i], lm, lp, cm, cp);
            hn[i] = A0[i] + cE[i] * h[i] + cWm[i] * hm + cWp[i] * hp
                  + cCm[i] * cm + cCp[i] * cp;
        }
        if (jg == 0) vstore(&HBS[wv * CC + c4], hn[0]);
        if (jg == 3) vstore(&HBE[wv * CC + c4], hn[3]);
        const f4 hLs = shfl4(hn[3], (l - 16) & 63);
        const f4 hRs = shfl4(hn[0], (l + 16) & 63);
        __syncthreads();   // B: h1 halos visible

        // PDE iter 2
        const f4 hL2 = (jg == 0) ? vload(&HBE[((wv + 7) & 7) * CC + c4]) : hLs;
        const f4 hR2 = (jg == 3) ? vload(&HBS[((wv + 1) & 7) * CC + c4]) : hRs;
        f4 h2v[NPT];
        #pragma unroll
        for (int i = 0; i < NPT; ++i) {
            const f4 hm = (i == 0)       ? hL2 : hn[i - 1];
            const f4 hp = (i == NPT - 1) ? hR2 : hn[i + 1];
            f4 cm, cp;
            croll(hn[i], lm, lp, cm, cp);
            h2v[i] = A0[i] + cE[i] * hn[i] + cWm[i] * hm + cWp[i] * hp
                   + cCm[i] * cm + cCp[i] * cp;
        }

        // epilogue: BN + ReLU (folds in registers)
        const long rowout = imgbase + (long)gr * RS;
        #pragma unroll
        for (int i = 0; i < NPT; ++i)
            vstore(out + rowout + oc[i + 1], vrelu(h2v[i] * s_o + b_o));
    }
}

extern "C" void kernel_launch(void* const* d_in, const int* in_sizes, int n_in,
                              void* d_out, int out_size, void* d_ws, size_t ws_size,
                              hipStream_t stream) {
    const float* s0   = (const float*)d_in[0];
    const float* kg   = (const float*)d_in[1];
    const float* kg1  = (const float*)d_in[2];
    const float* kDx  = (const float*)d_in[3];
    const float* kDy  = (const float*)d_in[4];
    const float* bng  = (const float*)d_in[5];
    const float* bng1 = (const float*)d_in[6];
    const float* bnDx = (const float*)d_in[7];
    const float* bnDy = (const float*)d_in[8];
    const float* bno  = (const float*)d_in[9];
    float* out = (float*)d_out;

    dim3 grid(16 * (HH / ROWS));   // 256 blocks = 1 per CU, 8 rows each
    dim3 block(BS);
    diffusion_fused<<<grid, block, 0, stream>>>(
        s0, kg, kg1, kDx, kDy, bng, bng1, bnDx, bnDy, bno, out);
}

// Round 11
// 190.649 us; speedup vs baseline: 1.1632x; 1.1632x over previous
//
#include <hip/hip_runtime.h>

#define HH 128
#define WW 128
#define CC 64
#define BS 512
#define RS (WW * CC)    // row stride in floats
#define NPT 4           // contiguous w-points per thread
#define NSTRIP 32       // strips per row (NSTRIP * NPT == WW)
#define ROWS 8          // image rows per block (grid = 16*128/ROWS = 256 = 1/CU)

typedef float f4 __attribute__((ext_vector_type(4)));

static __device__ __forceinline__ f4 vload(const float* p) {
    return *reinterpret_cast<const f4*>(p);
}
static __device__ __forceinline__ void vstore(float* p, f4 v) {
    *reinterpret_cast<f4*>(p) = v;
}
static __device__ __forceinline__ f4 vrelu(f4 a) {
    f4 r;
    #pragma unroll
    for (int i = 0; i < 4; ++i) r[i] = fmaxf(a[i], 0.f);
    return r;
}
static __device__ __forceinline__ f4 vrsq_eps(f4 a) {   // 1/sqrt(a+eps), HW v_rsq_f32
    f4 r;
    #pragma unroll
    for (int i = 0; i < 4; ++i) r[i] = __builtin_amdgcn_rsqf(a[i] + 1e-3f);
    return r;
}
static __device__ __forceinline__ f4 vrcp(f4 a) {       // 1/a, HW v_rcp_f32
    f4 r;
    #pragma unroll
    for (int i = 0; i < 4; ++i) r[i] = __builtin_amdgcn_rcpf(a[i]);
    return r;
}
// Channel-roll (c+-1 wrap over 64 ch) of an f4 held across a 16-lane cq group.
static __device__ __forceinline__ void croll(f4 v, int lm, int lp, f4& cm, f4& cp) {
    const float m3 = __shfl(v.w, lm);
    const float p0 = __shfl(v.x, lp);
    cm.x = m3;  cm.y = v.x; cm.z = v.y; cm.w = v.z;
    cp.x = v.y; cp.y = v.z; cp.z = v.w; cp.w = p0;
}
static __device__ __forceinline__ f4 shfl4(f4 v, int lane) {
    f4 r;
    r.x = __shfl(v.x, lane);
    r.y = __shfl(v.y, lane);
    r.z = __shfl(v.z, lane);
    r.w = __shfl(v.w, lane);
    return r;
}

// async global->LDS DMA, 16 B/lane; LDS dest = wave-uniform base + lane*16 (m03/m97)
static __device__ __forceinline__ void gld_lds16(const float* g, float* l) {
    __builtin_amdgcn_global_load_lds(
        (const __attribute__((address_space(1))) void*)g,
        (__attribute__((address_space(3))) void*)l,
        16, 0, 0);
}
// copy one 32 KB image row into an LDS ring slot (4 x 1 KB chunks per wave)
static __device__ __forceinline__ void stage_row(const float* g, float* l,
                                                 int wv, int ln) {
    #pragma unroll
    for (int it = 0; it < 4; ++it) {
        const int off = (it * 8 + wv) * 256;   // float offset, wave-uniform
        gld_lds16(g + off + ln * 4, l + off);
    }
}

// 3 taps (one conv row): g/g1 weights from REGISTERS (static idx), Dx/Dy from LDS.
template<int KBASE, bool CENTER>
static __device__ __forceinline__ void conv_taps(
    const float* R, const f4* wgr, const f4* wg1r, const float* WTS,
    const int* oc, bool zl, bool zr, int c4,
    f4* ag, f4* ag1, f4* adx, f4* ady, f4* h)
{
    f4 in[6];
    #pragma unroll
    for (int jj = 0; jj < 6; ++jj) in[jj] = vload(R + oc[jj]);
    if (zl) in[0] = (f4)0.f;     // zero pad, cndmask
    if (zr) in[5] = (f4)0.f;
    if (CENTER) {
        #pragma unroll
        for (int i = 0; i < NPT; ++i) h[i] = in[i + 1];   // f
    }
    #pragma unroll
    for (int dw = 0; dw < 3; ++dw) {
        const int kk = KBASE + dw;                        // compile-time
        const f4 wg  = wgr[kk];
        const f4 wg1 = wg1r[kk];
        const f4 wdx = vload(WTS + kk * CC + c4);
        const f4 wdy = vload(WTS + (9 + kk) * CC + c4);
        #pragma unroll
        for (int i = 0; i < NPT; ++i) {
            ag[i]  += in[dw + i] * wg;
            ag1[i] += in[dw + i] * wg1;
            adx[i] += in[dw + i] * wdx;
            ady[i] += in[dw + i] * wdy;
        }
    }
}

// NOTE (r2/r10): __launch_bounds__ 2nd arg behaves as min BLOCKS/CU on this
// toolchain (r10: (512,2)->cap 128; r2: (1024,8)->cap 32). LDS (140 KB) already
// limits to 1 block/CU, so (BS,1) raises the VGPR cap to 256 at zero cost.
// NOTE (r8/r10): weight promotion spilled ONLY because the cap was 128.
// This round: r9 structure + g/g1 weights in registers (~72 VGPR), BNF in LDS.
__global__ __launch_bounds__(BS, 1) void diffusion_fused(
    const float* __restrict__ s0,
    const float* __restrict__ kg,  const float* __restrict__ kg1,
    const float* __restrict__ kDx, const float* __restrict__ kDy,
    const float* __restrict__ bng,  const float* __restrict__ bng1,
    const float* __restrict__ bnDx, const float* __restrict__ bnDy,
    const float* __restrict__ bn_out,
    float* __restrict__ out)
{
    __shared__ __attribute__((aligned(16))) float ring[4][RS];     // 128 KB, slot(row x) = x&3
    __shared__ __attribute__((aligned(16))) float GHS[8 * CC];     // 2 KB g first-col per wave
    __shared__ __attribute__((aligned(16))) float GHE[8 * CC];     // 2 KB g last-col per wave
    __shared__ __attribute__((aligned(16))) float HBS[8 * CC];     // 2 KB h1 first-col per wave
    __shared__ __attribute__((aligned(16))) float HBE[8 * CC];     // 2 KB h1 last-col per wave
    __shared__ __attribute__((aligned(16))) float WTS[2 * 9 * CC]; // 4.5 KB Dx/Dy weights
    __shared__ __attribute__((aligned(16))) float BNF[10 * CC];    // 2.5 KB folded BN params

    const int t  = threadIdx.x;
    const int cq = t & 15;
    const int c4 = cq << 2;              // channels c4..c4+3
    const int s  = t >> 4;               // strip 0..31
    const int w0 = s << 2;               // output columns w0..w0+3
    const int l  = t & 63;
    const int wv = t >> 6;               // wave 0..7 (wave owns strips 4wv..4wv+3)
    const int jg = l >> 4;               // strip slot within wave 0..3
    const int lm = (l & 48) | ((l + 15) & 15);   // channel-roll shuffle lanes
    const int lp = (l & 48) | ((l + 1)  & 15);

    const int bid = blockIdx.x;
    const int img = bid >> 4;            // 16 row-groups per image
    const int r0  = (bid & 15) << 3;     // first row of this block's group
    const long imgbase = (long)img * HH * RS;

    // column offsets for the 6-column window w0-1 .. w0+4 (clamped; pad zeroed)
    const bool zl = (s == 0), zr = (s == NSTRIP - 1);
    int oc[6];
    oc[0] = (zl ? 0 : (w0 - 1)) * CC + c4;
    #pragma unroll
    for (int j = 1; j <= 4; ++j) oc[j] = (w0 + j - 1) * CC + c4;
    oc[5] = (zr ? (WW - 1) : (w0 + 4)) * CC + c4;
    const int wmo = ((w0 - 1) & (WW - 1)) * CC + c4;   // wrap left col (roll semantics)
    const int wpo = ((w0 + 4) & (WW - 1)) * CC + c4;   // wrap right col

    // ---- prologue ----
    if (r0 > 0)
        stage_row(s0 + imgbase + (long)(r0 - 1) * RS, ring[(r0 - 1) & 3], wv, l);
    stage_row(s0 + imgbase + (long)r0 * RS,       ring[r0 & 3],       wv, l);
    stage_row(s0 + imgbase + (long)(r0 + 1) * RS, ring[(r0 + 1) & 3], wv, l);

    // g/g1 weights -> registers (once per block; all indexing static via KBASE)
    f4 wgr[9], wg1r[9];
    #pragma unroll
    for (int kk = 0; kk < 9; ++kk) {
        wgr[kk]  = vload(kg  + kk * CC + c4);
        wg1r[kk] = vload(kg1 + kk * CC + c4);
    }
    // Dx/Dy weights -> LDS (288 f4 slots)
    if (t < 288) {
        const int q   = (t >= 144);
        const int rem = t - q * 144;
        const int kk  = rem >> 4;
        const int cc4 = (rem & 15) << 2;
        const float* src = q ? kDy : kDx;
        vstore(&WTS[(q * 9 + kk) * CC + cc4], vload(src + kk * CC + cc4));
    }
    if (s == 0) {   // BN folds -> LDS: y = S*x + B (2*DT folded into Dx/Dy)
        #define BNF1(P, K, SC) { \
            const f4 ga = vload((P) + c4);       const f4 be = vload((P) + 64 + c4);  \
            const f4 mu = vload((P) + 128 + c4); const f4 va = vload((P) + 192 + c4); \
            const f4 sc0 = ga * vrsq_eps(va);                                         \
            vstore(&BNF[(2 * (K)) * CC + c4], sc0 * (SC));                            \
            vstore(&BNF[(2 * (K) + 1) * CC + c4], (be - mu * sc0) * (SC)); }
        BNF1(bng,    0, 1.0f);
        BNF1(bng1,   1, 1.0f);
        BNF1(bnDx,   2, 0.4f);
        BNF1(bnDy,   3, 0.4f);
        BNF1(bn_out, 4, 1.0f);
        #undef BNF1
    }
    __syncthreads();   // prologue staging + WTS/BNF visible

    // ---- row loop: 2 barriers/row; stage(gr+2) issued at TOP, drains at A ----
    for (int j = 0; j < ROWS; ++j) {
        const int gr = r0 + j;
        // slot (gr+2)&3 == slot (gr-2)&3: last read in row j-1's conv, which
        // retired before row j-1's barrier A -> safe to overwrite here.
        if (j < ROWS - 1 && gr + 2 < HH)
            stage_row(s0 + imgbase + (long)(gr + 2) * RS, ring[(gr + 2) & 3], wv, l);

        const bool rowm = (gr > 0), rowp = (gr < HH - 1);
        const float* Rm = ring[(gr + 3) & 3];   // row gr-1
        const float* Rc = ring[gr & 3];         // row gr
        const float* Rp = ring[(gr + 1) & 3];   // row gr+1

        f4 ag[NPT], ag1[NPT], adx[NPT], ady[NPT], h[NPT];
        #pragma unroll
        for (int i = 0; i < NPT; ++i) {
            ag[i] = (f4)0.f; ag1[i] = (f4)0.f; adx[i] = (f4)0.f; ady[i] = (f4)0.f;
        }
        if (rowm) conv_taps<0, false>(Rm, wgr, wg1r, WTS, oc, zl, zr, c4, ag, ag1, adx, ady, h);
        conv_taps<3, true >(Rc, wgr, wg1r, WTS, oc, zl, zr, c4, ag, ag1, adx, ady, h);
        if (rowp) conv_taps<6, false>(Rp, wgr, wg1r, WTS, oc, zl, zr, c4, ag, ag1, adx, ady, h);

        // f W-edge neighbors straight from resident ring row (no barrier dep)
        const f4 hL = vload(Rc + wmo);
        const f4 hR = vload(Rc + wpo);

        // BN apply + g/g1; publish wave-edge g halos
        const f4 s_g  = vload(&BNF[0 * CC + c4]), b_g  = vload(&BNF[1 * CC + c4]);
        const f4 s_g1 = vload(&BNF[2 * CC + c4]), b_g1 = vload(&BNF[3 * CC + c4]);
        const f4 s_dx = vload(&BNF[4 * CC + c4]), b_dx = vload(&BNF[5 * CC + c4]);
        const f4 s_dy = vload(&BNF[6 * CC + c4]), b_dy = vload(&BNF[7 * CC + c4]);
        f4 g[NPT], g1[NPT];
        #pragma unroll
        for (int i = 0; i < NPT; ++i) {
            g[i]  = vrelu(ag[i]  * s_g  + b_g );
            g1[i] = vrelu(ag1[i] * s_g1 + b_g1);
        }
        if (jg == 0) vstore(&GHS[wv * CC + c4], g[0]);
        if (jg == 3) vstore(&GHE[wv * CC + c4], g[3]);
        // wave-sync shuffles for interior strip edges
        const f4 gLs = shfl4(g[3], (l - 16) & 63);
        const f4 gRs = shfl4(g[0], (l + 16) & 63);

        // per-point PDE coefficients (verbatim r5/r7/r9 numerics)
        f4 cWm[NPT], cWp[NPT], cCm[NPT], cCp[NPT], A0[NPT], PqD[NPT], uv[NPT];
        #pragma unroll
        for (int i = 0; i < NPT; ++i) {
            const f4 tbx = vrelu(adx[i] * s_dx + b_dx);   // = 2*DT*Dx
            const f4 tby = vrelu(ady[i] * s_dy + b_dy);   // = 2*DT*Dy
            const f4 Dv  = vrcp((f4)1.f + tbx + tby);
            const f4 Ax  = g[i]  * 0.2f;
            const f4 Ay  = g1[i] * 0.2f;
            cWm[i] = Dv * (tbx - Ax);
            cWp[i] = Dv * (tbx + Ax);
            cCm[i] = Dv * (tby - Ay);
            cCp[i] = Dv * (tby + Ay);
            A0[i]  = Dv * h[i] * ((f4)1.4f - tbx - tby);  // h0 == f both iters (K=2 lag)
            PqD[i] = Dv * (-0.4f);
            f4 cm, cp;
            croll(g1[i], lm, lp, cm, cp);
            uv[i] = 0.5f * (cm - cp);                     // vy part
        }
        uv[0] -= 0.5f * g[1];
        uv[1] += 0.5f * (g[0] - g[2]);
        uv[2] += 0.5f * (g[1] - g[3]);
        uv[3] += 0.5f * g[2];
        __syncthreads();   // A: g halos visible; stage DMA for row gr+2 drained

        // cE from ux edges (LDS only for wave-edge strips)
        const f4 gL = (jg == 0) ? vload(&GHE[((wv + 7) & 7) * CC + c4]) : gLs;
        const f4 gR = (jg == 3) ? vload(&GHS[((wv + 1) & 7) * CC + c4]) : gRs;
        f4 cE[NPT];
        cE[0] = PqD[0] * (uv[0] + 0.5f * gL);
        cE[1] = PqD[1] * uv[1];
        cE[2] = PqD[2] * uv[2];
        cE[3] = PqD[3] * (uv[3] - 0.5f * gR);

        // PDE iter 1 (h == f)
        f4 hn[NPT];
        #pragma unroll
        for (int i = 0; i < NPT; ++i) {
            const f4 hm = (i == 0)       ? hL : h[i - 1];
            const f4 hp = (i == NPT - 1) ? hR : h[i + 1];
            f4 cm, cp;
            croll(h[i], lm, lp, cm, cp);
            hn[i] = A0[i] + cE[i] * h[i] + cWm[i] * hm + cWp[i] * hp
                  + cCm[i] * cm + cCp[i] * cp;
        }
        if (jg == 0) vstore(&HBS[wv * CC + c4], hn[0]);
        if (jg == 3) vstore(&HBE[wv * CC + c4], hn[3]);
        const f4 hLs = shfl4(hn[3], (l - 16) & 63);
        const f4 hRs = shfl4(hn[0], (l + 16) & 63);
        __syncthreads();   // B: h1 halos visible

        // PDE iter 2
        const f4 hL2 = (jg == 0) ? vload(&HBE[((wv + 7) & 7) * CC + c4]) : hLs;
        const f4 hR2 = (jg == 3) ? vload(&HBS[((wv + 1) & 7) * CC + c4]) : hRs;
        f4 h2v[NPT];
        #pragma unroll
        for (int i = 0; i < NPT; ++i) {
            const f4 hm = (i == 0)       ? hL2 : hn[i - 1];
            const f4 hp = (i == NPT - 1) ? hR2 : hn[i + 1];
            f4 cm, cp;
            croll(hn[i], lm, lp, cm, cp);
            h2v[i] = A0[i] + cE[i] * hn[i] + cWm[i] * hm + cWp[i] * hp
                   + cCm[i] * cm + cCp[i] * cp;
        }

        // epilogue: BN + ReLU
        const f4 s_o = vload(&BNF[8 * CC + c4]), b_o = vload(&BNF[9 * CC + c4]);
        const long rowout = imgbase + (long)gr * RS;
        #pragma unroll
        for (int i = 0; i < NPT; ++i)
            vstore(out + rowout + oc[i + 1], vrelu(h2v[i] * s_o + b_o));
    }
}

extern "C" void kernel_launch(void* const* d_in, const int* in_sizes, int n_in,
                              void* d_out, int out_size, void* d_ws, size_t ws_size,
                              hipStream_t stream) {
    const float* s0   = (const float*)d_in[0];
    const float* kg   = (const float*)d_in[1];
    const float* kg1  = (const float*)d_in[2];
    const float* kDx  = (const float*)d_in[3];
    const float* kDy  = (const float*)d_in[4];
    const float* bng  = (const float*)d_in[5];
    const float* bng1 = (const float*)d_in[6];
    const float* bnDx = (const float*)d_in[7];
    const float* bnDy = (const float*)d_in[8];
    const float* bno  = (const float*)d_in[9];
    float* out = (float*)d_out;

    dim3 grid(16 * (HH / ROWS));   // 256 blocks = 1 per CU, 8 rows each
    dim3 block(BS);
    diffusion_fused<<<grid, block, 0, stream>>>(
        s0, kg, kg1, kDx, kDy, bng, bng1, bnDx, bnDy, bno, out);
}

// Round 12
// 152.014 us; speedup vs baseline: 1.4588x; 1.2542x over previous
//
#include <hip/hip_runtime.h>

#define HH 128
#define WW 128
#define CC 64
#define BS 512
#define RS (WW * CC)    // row stride in floats
#define NPT 4           // contiguous w-points per thread
#define NSTRIP 32       // strips per row (NSTRIP * NPT == WW)
#define ROWS 8          // image rows per block (grid = 16*128/ROWS = 256 = 1/CU)

typedef float f4 __attribute__((ext_vector_type(4)));

static __device__ __forceinline__ f4 vload(const float* p) {
    return *reinterpret_cast<const f4*>(p);
}
static __device__ __forceinline__ void vstore(float* p, f4 v) {
    *reinterpret_cast<f4*>(p) = v;
}
static __device__ __forceinline__ f4 vrelu(f4 a) {
    f4 r;
    #pragma unroll
    for (int i = 0; i < 4; ++i) r[i] = fmaxf(a[i], 0.f);
    return r;
}
static __device__ __forceinline__ f4 vrsq_eps(f4 a) {   // 1/sqrt(a+eps), HW v_rsq_f32
    f4 r;
    #pragma unroll
    for (int i = 0; i < 4; ++i) r[i] = __builtin_amdgcn_rsqf(a[i] + 1e-3f);
    return r;
}
static __device__ __forceinline__ f4 vrcp(f4 a) {       // 1/a, HW v_rcp_f32
    f4 r;
    #pragma unroll
    for (int i = 0; i < 4; ++i) r[i] = __builtin_amdgcn_rcpf(a[i]);
    return r;
}
// Channel-roll (c+-1 wrap over 64 ch) of an f4 held across a 16-lane cq group.
static __device__ __forceinline__ void croll(f4 v, int lm, int lp, f4& cm, f4& cp) {
    const float m3 = __shfl(v.w, lm);
    const float p0 = __shfl(v.x, lp);
    cm.x = m3;  cm.y = v.x; cm.z = v.y; cm.w = v.z;
    cp.x = v.y; cp.y = v.z; cp.z = v.w; cp.w = p0;
}
static __device__ __forceinline__ f4 shfl4(f4 v, int lane) {
    f4 r;
    r.x = __shfl(v.x, lane);
    r.y = __shfl(v.y, lane);
    r.z = __shfl(v.z, lane);
    r.w = __shfl(v.w, lane);
    return r;
}

// async global->LDS DMA, 16 B/lane; LDS dest = wave-uniform base + lane*16 (m03/m97)
static __device__ __forceinline__ void gld_lds16(const float* g, float* l) {
    __builtin_amdgcn_global_load_lds(
        (const __attribute__((address_space(1))) void*)g,
        (__attribute__((address_space(3))) void*)l,
        16, 0, 0);
}
// copy one 32 KB image row into an LDS ring slot (4 x 1 KB chunks per wave)
static __device__ __forceinline__ void stage_row(const float* g, float* l,
                                                 int wv, int ln) {
    #pragma unroll
    for (int it = 0; it < 4; ++it) {
        const int off = (it * 8 + wv) * 256;   // float offset, wave-uniform
        gld_lds16(g + off + ln * 4, l + off);
    }
}

// 3 taps (one conv row), all 4 kernels' (pre-scaled) weights from LDS.
template<int KBASE, bool CENTER>
static __device__ __forceinline__ void conv_taps(
    const float* R, const float* WTS, const int* oc,
    bool zl, bool zr, int c4,
    f4* ag, f4* ag1, f4* adx, f4* ady, f4* h)
{
    f4 in[6];
    #pragma unroll
    for (int jj = 0; jj < 6; ++jj) in[jj] = vload(R + oc[jj]);
    if (zl) in[0] = (f4)0.f;     // zero pad, cndmask
    if (zr) in[5] = (f4)0.f;
    if (CENTER) {
        #pragma unroll
        for (int i = 0; i < NPT; ++i) h[i] = in[i + 1];   // f
    }
    #pragma unroll
    for (int dw = 0; dw < 3; ++dw) {
        const int kk = KBASE + dw;                        // compile-time
        const f4 wg  = vload(WTS + (0 * 9 + kk) * CC + c4);
        const f4 wg1 = vload(WTS + (1 * 9 + kk) * CC + c4);
        const f4 wdx = vload(WTS + (2 * 9 + kk) * CC + c4);
        const f4 wdy = vload(WTS + (3 * 9 + kk) * CC + c4);
        #pragma unroll
        for (int i = 0; i < NPT; ++i) {
            ag[i]  += in[dw + i] * wg;
            ag1[i] += in[dw + i] * wg1;
            adx[i] += in[dw + i] * wdx;
            ady[i] += in[dw + i] * wdy;
        }
    }
}

// NOTE (r2/r10/r11): VGPR cap is empirically 128 on this toolchain regardless of
// __launch_bounds__; register promotion of weights is DEAD (3 spill rounds).
// NOTE (r9, best=58us): ring-4 + stage-at-top + 2 barriers/row, weights in LDS.
// This round: BN SCALES folded into the staged weights (exact: s*sum(w x) =
// sum((w s) x); relu commutes with +0.4 scale), biases (4 f4 = 16 VGPR) in
// registers -> 10 BNF ds_reads/row removed at ~+16 VGPR (104 -> ~120 < 128).
__global__ __launch_bounds__(BS) void diffusion_fused(
    const float* __restrict__ s0,
    const float* __restrict__ kg,  const float* __restrict__ kg1,
    const float* __restrict__ kDx, const float* __restrict__ kDy,
    const float* __restrict__ bng,  const float* __restrict__ bng1,
    const float* __restrict__ bnDx, const float* __restrict__ bnDy,
    const float* __restrict__ bn_out,
    float* __restrict__ out)
{
    __shared__ __attribute__((aligned(16))) float ring[4][RS];     // 128 KB, slot(row x) = x&3
    __shared__ __attribute__((aligned(16))) float GHS[8 * CC];     // 2 KB g first-col per wave
    __shared__ __attribute__((aligned(16))) float GHE[8 * CC];     // 2 KB g last-col per wave
    __shared__ __attribute__((aligned(16))) float HBS[8 * CC];     // 2 KB h1 first-col per wave
    __shared__ __attribute__((aligned(16))) float HBE[8 * CC];     // 2 KB h1 last-col per wave
    __shared__ __attribute__((aligned(16))) float WTS[4 * 9 * CC]; // 9 KB PRE-SCALED weights
    __shared__ __attribute__((aligned(16))) float BNO[2 * CC];     // 0.5 KB out-BN fold

    const int t  = threadIdx.x;
    const int cq = t & 15;
    const int c4 = cq << 2;              // channels c4..c4+3
    const int s  = t >> 4;               // strip 0..31
    const int w0 = s << 2;               // output columns w0..w0+3
    const int l  = t & 63;
    const int wv = t >> 6;               // wave 0..7 (wave owns strips 4wv..4wv+3)
    const int jg = l >> 4;               // strip slot within wave 0..3
    const int lm = (l & 48) | ((l + 15) & 15);   // channel-roll shuffle lanes
    const int lp = (l & 48) | ((l + 1)  & 15);

    const int bid = blockIdx.x;
    const int img = bid >> 4;            // 16 row-groups per image
    const int r0  = (bid & 15) << 3;     // first row of this block's group
    const long imgbase = (long)img * HH * RS;

    // column offsets for the 6-column window w0-1 .. w0+4 (clamped; pad zeroed)
    const bool zl = (s == 0), zr = (s == NSTRIP - 1);
    int oc[6];
    oc[0] = (zl ? 0 : (w0 - 1)) * CC + c4;
    #pragma unroll
    for (int j = 1; j <= 4; ++j) oc[j] = (w0 + j - 1) * CC + c4;
    oc[5] = (zr ? (WW - 1) : (w0 + 4)) * CC + c4;
    const int wmo = ((w0 - 1) & (WW - 1)) * CC + c4;   // wrap left col (roll semantics)
    const int wpo = ((w0 + 4) & (WW - 1)) * CC + c4;   // wrap right col

    // ---- prologue ----
    if (r0 > 0)
        stage_row(s0 + imgbase + (long)(r0 - 1) * RS, ring[(r0 - 1) & 3], wv, l);
    stage_row(s0 + imgbase + (long)r0 * RS,       ring[r0 & 3],       wv, l);
    stage_row(s0 + imgbase + (long)(r0 + 1) * RS, ring[(r0 + 1) & 3], wv, l);

    {   // weights -> LDS, PRE-SCALED by the BN scale of their branch
        const float* wsrc[4] = { kg, kg1, kDx, kDy };
        const float* bsrc[4] = { bng, bng1, bnDx, bnDy };
        #pragma unroll
        for (int base = 0; base < 576; base += BS) {
            const int slot = base + t;
            if (slot < 576) {
                const int q   = slot / 144;
                const int rem = slot - q * 144;
                const int kk  = rem >> 4;
                const int cc4 = (rem & 15) << 2;
                const f4 ga = vload(bsrc[q] + cc4);
                const f4 va = vload(bsrc[q] + 192 + cc4);
                const float qs = (q >= 2) ? 0.4f : 1.0f;   // 2*DT fold for Dx/Dy
                const f4 sc = ga * vrsq_eps(va) * qs;
                vstore(&WTS[(q * 9 + kk) * CC + cc4],
                       vload(wsrc[q] + kk * CC + cc4) * sc);
            }
        }
    }
    // biases -> registers (per-thread, 4 f4 = 16 VGPR)
    #define BIAS(P, B, SC) { \
        const f4 ga = vload((P) + c4);       const f4 be = vload((P) + 64 + c4);  \
        const f4 mu = vload((P) + 128 + c4); const f4 va = vload((P) + 192 + c4); \
        B = (be - mu * (ga * vrsq_eps(va))) * (SC); }
    f4 b_g, b_g1, b_dx, b_dy;
    BIAS(bng,  b_g,  1.0f);
    BIAS(bng1, b_g1, 1.0f);
    BIAS(bnDx, b_dx, 0.4f);
    BIAS(bnDy, b_dy, 0.4f);
    if (s == 0) {   // out-BN fold -> tiny LDS (read 2x per row)
        f4 S, B;
        BIAS(bn_out, B, 1.0f);
        {
            const f4 ga = vload(bn_out + c4);
            const f4 va = vload(bn_out + 192 + c4);
            S = ga * vrsq_eps(va);
        }
        vstore(&BNO[c4], S);
        vstore(&BNO[CC + c4], B);
    }
    #undef BIAS
    __syncthreads();   // prologue staging + WTS/BNO visible

    // ---- row loop: 2 barriers/row; stage(gr+2) issued at TOP, drains at A ----
    for (int j = 0; j < ROWS; ++j) {
        const int gr = r0 + j;
        // slot (gr+2)&3 == slot (gr-2)&3: last read in row j-1's conv, which
        // retired before row j-1's barrier A -> safe to overwrite here.
        if (j < ROWS - 1 && gr + 2 < HH)
            stage_row(s0 + imgbase + (long)(gr + 2) * RS, ring[(gr + 2) & 3], wv, l);

        const bool rowm = (gr > 0), rowp = (gr < HH - 1);
        const float* Rm = ring[(gr + 3) & 3];   // row gr-1
        const float* Rc = ring[gr & 3];         // row gr
        const float* Rp = ring[(gr + 1) & 3];   // row gr+1

        f4 ag[NPT], ag1[NPT], adx[NPT], ady[NPT], h[NPT];
        #pragma unroll
        for (int i = 0; i < NPT; ++i) {
            ag[i] = (f4)0.f; ag1[i] = (f4)0.f; adx[i] = (f4)0.f; ady[i] = (f4)0.f;
        }
        if (rowm) conv_taps<0, false>(Rm, WTS, oc, zl, zr, c4, ag, ag1, adx, ady, h);
        conv_taps<3, true >(Rc, WTS, oc, zl, zr, c4, ag, ag1, adx, ady, h);
        if (rowp) conv_taps<6, false>(Rp, WTS, oc, zl, zr, c4, ag, ag1, adx, ady, h);

        // f W-edge neighbors straight from resident ring row (no barrier dep)
        const f4 hL = vload(Rc + wmo);
        const f4 hR = vload(Rc + wpo);

        // BN apply (scales pre-folded into weights): g = relu(acc + bias)
        f4 g[NPT], g1[NPT];
        #pragma unroll
        for (int i = 0; i < NPT; ++i) {
            g[i]  = vrelu(ag[i]  + b_g );
            g1[i] = vrelu(ag1[i] + b_g1);
        }
        if (jg == 0) vstore(&GHS[wv * CC + c4], g[0]);
        if (jg == 3) vstore(&GHE[wv * CC + c4], g[3]);
        // wave-sync shuffles for interior strip edges
        const f4 gLs = shfl4(g[3], (l - 16) & 63);
        const f4 gRs = shfl4(g[0], (l + 16) & 63);

        // per-point PDE coefficients (same numerics as r5/r7/r9)
        f4 cWm[NPT], cWp[NPT], cCm[NPT], cCp[NPT], A0[NPT], PqD[NPT], uv[NPT];
        #pragma unroll
        for (int i = 0; i < NPT; ++i) {
            const f4 tbx = vrelu(adx[i] + b_dx);   // = 2*DT*Dx
            const f4 tby = vrelu(ady[i] + b_dy);   // = 2*DT*Dy
            const f4 Dv  = vrcp((f4)1.f + tbx + tby);
            const f4 Ax  = g[i]  * 0.2f;
            const f4 Ay  = g1[i] * 0.2f;
            cWm[i] = Dv * (tbx - Ax);
            cWp[i] = Dv * (tbx + Ax);
            cCm[i] = Dv * (tby - Ay);
            cCp[i] = Dv * (tby + Ay);
            A0[i]  = Dv * h[i] * ((f4)1.4f - tbx - tby);  // h0 == f both iters (K=2 lag)
            PqD[i] = Dv * (-0.4f);
            f4 cm, cp;
            croll(g1[i], lm, lp, cm, cp);
            uv[i] = 0.5f * (cm - cp);                     // vy part
        }
        uv[0] -= 0.5f * g[1];
        uv[1] += 0.5f * (g[0] - g[2]);
        uv[2] += 0.5f * (g[1] - g[3]);
        uv[3] += 0.5f * g[2];
        __syncthreads();   // A: g halos visible; stage DMA for row gr+2 drained

        // cE from ux edges (LDS only for wave-edge strips)
        const f4 gL = (jg == 0) ? vload(&GHE[((wv + 7) & 7) * CC + c4]) : gLs;
        const f4 gR = (jg == 3) ? vload(&GHS[((wv + 1) & 7) * CC + c4]) : gRs;
        f4 cE[NPT];
        cE[0] = PqD[0] * (uv[0] + 0.5f * gL);
        cE[1] = PqD[1] * uv[1];
        cE[2] = PqD[2] * uv[2];
        cE[3] = PqD[3] * (uv[3] - 0.5f * gR);

        // PDE iter 1 (h == f)
        f4 hn[NPT];
        #pragma unroll
        for (int i = 0; i < NPT; ++i) {
            const f4 hm = (i == 0)       ? hL : h[i - 1];
            const f4 hp = (i == NPT - 1) ? hR : h[i + 1];
            f4 cm, cp;
            croll(h[i], lm, lp, cm, cp);
            hn[i] = A0[i] + cE[i] * h[i] + cWm[i] * hm + cWp[i] * hp
                  + cCm[i] * cm + cCp[i] * cp;
        }
        if (jg == 0) vstore(&HBS[wv * CC + c4], hn[0]);
        if (jg == 3) vstore(&HBE[wv * CC + c4], hn[3]);
        const f4 hLs = shfl4(hn[3], (l - 16) & 63);
        const f4 hRs = shfl4(hn[0], (l + 16) & 63);
        __syncthreads();   // B: h1 halos visible

        // PDE iter 2
        const f4 hL2 = (jg == 0) ? vload(&HBE[((wv + 7) & 7) * CC + c4]) : hLs;
        const f4 hR2 = (jg == 3) ? vload(&HBS[((wv + 1) & 7) * CC + c4]) : hRs;
        f4 h2v[NPT];
        #pragma unroll
        for (int i = 0; i < NPT; ++i) {
            const f4 hm = (i == 0)       ? hL2 : hn[i - 1];
            const f4 hp = (i == NPT - 1) ? hR2 : hn[i + 1];
            f4 cm, cp;
            croll(hn[i], lm, lp, cm, cp);
            h2v[i] = A0[i] + cE[i] * hn[i] + cWm[i] * hm + cWp[i] * hp
                   + cCm[i] * cm + cCp[i] * cp;
        }

        // epilogue: BN + ReLU (out-BN fold from tiny LDS)
        const f4 s_o = vload(&BNO[c4]), b_o = vload(&BNO[CC + c4]);
        const long rowout = imgbase + (long)gr * RS;
        #pragma unroll
        for (int i = 0; i < NPT; ++i)
            vstore(out + rowout + oc[i + 1], vrelu(h2v[i] * s_o + b_o));
    }
}

extern "C" void kernel_launch(void* const* d_in, const int* in_sizes, int n_in,
                              void* d_out, int out_size, void* d_ws, size_t ws_size,
                              hipStream_t stream) {
    const float* s0   = (const float*)d_in[0];
    const float* kg   = (const float*)d_in[1];
    const float* kg1  = (const float*)d_in[2];
    const float* kDx  = (const float*)d_in[3];
    const float* kDy  = (const float*)d_in[4];
    const float* bng  = (const float*)d_in[5];
    const float* bng1 = (const float*)d_in[6];
    const float* bnDx = (const float*)d_in[7];
    const float* bnDy = (const float*)d_in[8];
    const float* bno  = (const float*)d_in[9];
    float* out = (float*)d_out;

    dim3 grid(16 * (HH / ROWS));   // 256 blocks = 1 per CU, 8 rows each
    dim3 block(BS);
    diffusion_fused<<<grid, block, 0, stream>>>(
        s0, kg, kg1, kDx, kDy, bng, bng1, bnDx, bnDy, bno, out);
}